// Round 17
// baseline (82.247 us; speedup 1.0000x reference)
//
#include <hip/hip_runtime.h>
#include <hip/hip_bf16.h>

#define TDEPTH 6
#define NLEAF 64
#define NGATE 63
#define INF 512
#define OUTF 512
#define BATCH 1024
#define SPLITK 16
#define NPL 32        // real planes per K-slice (512/SPLITK)

typedef _Float16 f16;
typedef __attribute__((ext_vector_type(2)))  f16 f16x2;
typedef __attribute__((ext_vector_type(8)))  f16 f16x8;
typedef __attribute__((ext_vector_type(4)))  float f32x4;
typedef __attribute__((ext_vector_type(16))) float f32x16;

__device__ __forceinline__ f16x8 pack8h(f32x4 a, f32x4 b) {
  f16x8 w;
  w[0] = (f16)a[0]; w[1] = (f16)a[1]; w[2] = (f16)a[2]; w[3] = (f16)a[3];
  w[4] = (f16)b[0]; w[5] = (f16)b[1]; w[6] = (f16)b[2]; w[7] = (f16)b[3];
  return w;
}

// ---------------- kernel 1: leaf + coalesced pwh pack ----------------
// blocks [0,256): leaf.
// blocks [256,768): pw pack, SOURCE-coalesced: granule T (32B of f32 at
//   byte 32T) -> o=T>>12, i=(T>>3)&511, kg=T&7; dst tile (o>>5)*513+i,
//   row r=o&15, pos p=(8*((o>>4)&1)+kg)^r. 8 adjacent lanes (kg 0..7)
//   write one 128B line. Same tile layout as r16.
// block [768]: pb as plane 512 (same mapping).
__global__ __launch_bounds__(256) void prep_kernel(
    const float* __restrict__ x, const float* __restrict__ gw,
    const float* __restrict__ gb, const float* __restrict__ pw,
    const float* __restrict__ pb, float* __restrict__ leaf,
    f16* __restrict__ pwh) {
  const int tid = threadIdx.x;
  if (blockIdx.x < 256) {
    const int wid = tid >> 6, lane = tid & 63;
    const int b = blockIdx.x * 4 + wid;
    __shared__ float g[4][NLEAF];
    if (lane < NGATE) {
      const float* xr = x + (size_t)b * INF;
      float a0 = 0.f, a1 = 0.f, a2 = 0.f, a3 = 0.f;
      #pragma unroll 4
      for (int i = 0; i < INF; i += 4) {
        a0 += xr[i + 0] * gw[(i + 0) * NGATE + lane];
        a1 += xr[i + 1] * gw[(i + 1) * NGATE + lane];
        a2 += xr[i + 2] * gw[(i + 2) * NGATE + lane];
        a3 += xr[i + 3] * gw[(i + 3) * NGATE + lane];
      }
      float t = (a0 + a1) + (a2 + a3) + gb[lane];
      g[wid][lane] = 1.0f / (1.0f + __expf(-t));
    }
    __syncthreads();
    float p = 1.0f;
    #pragma unroll
    for (int d = 0; d < TDEPTH; d++) {
      int prefix = lane >> (TDEPTH - 1 - d);
      int node = (1 << d) - 1 + (prefix >> 1);
      float gv = g[wid][node];
      p *= (prefix & 1) ? (1.0f - gv) : gv;
    }
    leaf[(size_t)b * NLEAF + lane] = p;
    return;
  }
  if (blockIdx.x < 768) {  // pw: 512 blocks x 16 reps x 256 thr granules
    const unsigned base = (blockIdx.x - 256) * 4096;
    #pragma unroll
    for (int rep = 0; rep < 16; rep++) {
      const unsigned T = base + rep * 256 + tid;
      const unsigned o = T >> 12, rem = T & 4095;
      const unsigned i = rem >> 3, kg = rem & 7;
      const float* src = pw + (size_t)T * 8;          // fully coalesced
      f32x4 a = *(const f32x4*)src, b = *(const f32x4*)(src + 4);
      const unsigned r = o & 15;
      const unsigned p = ((((o >> 4) & 1) << 3) | kg) ^ r;
      char* dst = (char*)pwh + (((size_t)((o >> 5) * 513 + i)) << 12) +
                  r * 256 + p * 16;
      *(f16x8*)dst = pack8h(a, b);
    }
  } else {  // pb plane: 4096 granules
    #pragma unroll
    for (int rep = 0; rep < 16; rep++) {
      const unsigned T = rep * 256 + tid;
      const unsigned o = T >> 3, kg = T & 7;
      const float* src = pb + (size_t)T * 8;
      f32x4 a = *(const f32x4*)src, b = *(const f32x4*)(src + 4);
      const unsigned r = o & 15;
      const unsigned p = ((((o >> 4) & 1) << 3) | kg) ^ r;
      char* dst = (char*)pwh + (((size_t)((o >> 5) * 513 + 512)) << 12) +
                  r * 256 + p * 16;
      *(f16x8*)dst = pack8h(a, b);
    }
  }
}

// async 16B global -> LDS (wave-uniform LDS base; +lane*16 implicit)
__device__ __forceinline__ void gload_lds16(const void* g, void* l) {
  __builtin_amdgcn_global_load_lds(
      (const __attribute__((address_space(1))) void*)g,
      (__attribute__((address_space(3))) void*)l, 16, 0, 0);
}

// ---------------- kernel 2: barrier-free 1-wave GEMM, 4 waves/SIMD --------
// acc[o,b] += sum_l pw[o,i,l] * (x[b,i]*leaf[b,l]) via
// mfma(A = pw frag from LDS, B = lfb * xv8, C = acc). x in 32 packed-f16
// VGPRs (full unroll -> static index). 2x4KB LDS, depth-1 stage, counted
// vmcnt(4), lgkm WAR guard. NO barriers. 16 blocks/CU.
__global__ __launch_bounds__(64, 4) void gemm_kernel(
    const f16* __restrict__ pwh, const float* __restrict__ x,
    const float* __restrict__ leaf, float* __restrict__ partial) {
  __shared__ __align__(16) char Bsm[2][4096];

  const int lane = threadIdx.x;
  const int lo = lane & 31, half = lane >> 5;

  // XCD-chunked: XCD x covers s in {2x, 2x+1} (working set ~4.2MB ~ its L2)
  const int L = ((int)blockIdx.x & 7) * 512 + ((int)blockIdx.x >> 3);
  const int s = L >> 8;
  const int rem = L & 255;
  const int ot = rem >> 4, bt = rem & 15;
  const int b0 = bt * 64;
  const int cs = s * NPL;

  // x -> 32 packed regs: xu[t] = f16(x[b0+lo][cs+t]) | f16(x[b0+32+lo][..])<<16
  unsigned xu[NPL];
  {
    const float* x0 = x + (size_t)(b0 + lo) * INF + cs;
    const float* x1 = x + (size_t)(b0 + 32 + lo) * INF + cs;
    #pragma unroll
    for (int c4 = 0; c4 < NPL / 4; c4++) {
      f32x4 a = *(const f32x4*)(x0 + c4 * 4);
      f32x4 b = *(const f32x4*)(x1 + c4 * 4);
      #pragma unroll
      for (int j = 0; j < 4; j++) {
        unsigned la = (unsigned)__builtin_bit_cast(unsigned short, (f16)a[j]);
        unsigned lb = (unsigned)__builtin_bit_cast(unsigned short, (f16)b[j]);
        xu[c4 * 4 + j] = la | (lb << 16);
      }
    }
  }

  // resident leaf B-fragments (f16): col = b, k-octet = half
  f16x8 lfb[2][4];
  #pragma unroll
  for (int mt = 0; mt < 2; mt++) {
    const float* lr = leaf + (size_t)(b0 + mt * 32 + lo) * NLEAF + half * 8;
    #pragma unroll
    for (int t4 = 0; t4 < 4; t4++)
      lfb[mt][t4] = pack8h(*(const f32x4*)(lr + t4 * 16),
                           *(const f32x4*)(lr + t4 * 16 + 4));
  }

  // per-lane LDS read offsets (loop-invariant), conflict-benign geometry
  unsigned rdoff[4];
  {
    const unsigned r = (unsigned)(lo & 15);
    const unsigned hb = ((unsigned)(lo >> 4)) * 128 + (unsigned)half * 16;
    #pragma unroll
    for (int t4 = 0; t4 < 4; t4++)
      rdoff[t4] = r * 256 + ((hb + t4 * 32) ^ (r << 4));
  }

  const char* tb = (const char*)pwh + ((size_t)(ot * 513 + cs) << 12) +
                   (size_t)lane * 16;
  char* bufs[2] = {(char*)&Bsm[0][0], (char*)&Bsm[1][0]};

  f32x16 acc0 = (f32x16)(0.f), acc1 = (f32x16)(0.f);

  auto stage = [&](char* dstb, int t) {
    const char* srcb = tb + ((size_t)t << 12);
    #pragma unroll
    for (int j = 0; j < 4; j++)
      gload_lds16(srcb + j * 1024, dstb + j * 1024);
  };

  auto mfma_step = [&](const char* bufc, unsigned pr0, unsigned pr1) {
    f16x2 v0 = __builtin_bit_cast(f16x2, pr0);
    f16x2 v1 = __builtin_bit_cast(f16x2, pr1);
    f16x8 xv80 = __builtin_shufflevector(v0, v0, 0, 1, 0, 1, 0, 1, 0, 1);
    f16x8 xv81 = __builtin_shufflevector(v1, v1, 0, 1, 0, 1, 0, 1, 0, 1);
    #pragma unroll
    for (int t4 = 0; t4 < 4; t4++) {
      f16x8 af = *(const f16x8*)(bufc + rdoff[t4]);
      f16x8 s0 = lfb[0][t4] * xv80;
      f16x8 s1 = lfb[1][t4] * xv81;
      acc0 = __builtin_amdgcn_mfma_f32_32x32x16_f16(af, s0, acc0, 0, 0, 0);
      acc1 = __builtin_amdgcn_mfma_f32_32x32x16_f16(af, s1, acc1, 0, 0, 0);
    }
  };

  stage(bufs[0], 0);

  #pragma unroll
  for (int t = 0; t < NPL; t++) {
    // WAR guard: previous step's ds_reads done before overwriting its buffer
    __builtin_amdgcn_sched_barrier(0);
    asm volatile("s_waitcnt lgkmcnt(0)" ::: "memory");
    __builtin_amdgcn_sched_barrier(0);
    stage(bufs[(t + 1) & 1], t + 1);   // plane cs+t+1 always valid (<= 512)
    __builtin_amdgcn_sched_barrier(0);
    asm volatile("s_waitcnt vmcnt(4)" ::: "memory");  // stage(t) landed
    __builtin_amdgcn_sched_barrier(0);
    const unsigned u = xu[t];                          // static index
    unsigned p0 = u & 0xffffu;  p0 |= (p0 << 16);
    unsigned p1 = u >> 16;      p1 |= (p1 << 16);
    mfma_step(bufs[t & 1], p0, p1);
  }

  if (s == SPLITK - 1) {  // bias plane 512, staged at t=NPL-1 into bufs[0]
    __builtin_amdgcn_sched_barrier(0);
    asm volatile("s_waitcnt vmcnt(0)" ::: "memory");
    __builtin_amdgcn_sched_barrier(0);
    mfma_step(bufs[0], 0x3C003C00u, 0x3C003C00u);      // x == 1.0 (f16)
  }

  // epilogue: partial[s][o][b] (transposed), coalesced over b = lo
  float* dstb = partial + ((size_t)s * OUTF + ot * 32) * BATCH + b0;
  #pragma unroll
  for (int e = 0; e < 16; e++) {
    int row = (e & 3) + 8 * (e >> 2) + 4 * half;
    dstb[(size_t)row * BATCH + lo] = acc0[e];
    dstb[(size_t)row * BATCH + 32 + lo] = acc1[e];
  }
}

// ---------------- kernel 3: split-K reduce + transpose ----------------
// partial[s][o][b] -> out[b][o]
__global__ __launch_bounds__(256) void reduce_kernel(
    const float* __restrict__ partial, float* __restrict__ out) {
  __shared__ float tile[32][65];
  const int t = threadIdx.x;
  const int O0 = ((int)blockIdx.x >> 4) * 32;
  const int B0 = ((int)blockIdx.x & 15) * 64;
  #pragma unroll
  for (int rep = 0; rep < 8; rep++) {
    const int idx = rep * 256 + t;
    const int o = idx >> 6, b = idx & 63;
    float sum = 0.f;
    #pragma unroll
    for (int s = 0; s < SPLITK; s++)
      sum += partial[((size_t)s * OUTF + O0 + o) * BATCH + B0 + b];
    tile[o][b] = sum;
  }
  __syncthreads();
  #pragma unroll
  for (int rep = 0; rep < 8; rep++) {
    const int idx = rep * 256 + t;
    const int b = idx >> 5, o = idx & 31;
    out[(size_t)(B0 + b) * OUTF + O0 + o] = tile[o][b];
  }
}

extern "C" void kernel_launch(void* const* d_in, const int* in_sizes, int n_in,
                              void* d_out, int out_size, void* d_ws, size_t ws_size,
                              hipStream_t stream) {
  const float* x  = (const float*)d_in[0];
  const float* gw = (const float*)d_in[1];
  const float* gb = (const float*)d_in[2];
  const float* pw = (const float*)d_in[3];
  const float* pb = (const float*)d_in[4];
  float* out = (float*)d_out;

  float* leaf    = (float*)d_ws;                          // 256 KB
  f16*   pwh     = (f16*)((char*)d_ws + (256 << 10));     // 33.62 MB
  float* partial = (float*)((char*)d_ws + (256 << 10) + (size_t)16 * 513 * 4096);

  prep_kernel<<<769, 256, 0, stream>>>(x, gw, gb, pw, pb, leaf, pwh);
  gemm_kernel<<<4096, 64, 0, stream>>>(pwh, x, leaf, partial);
  reduce_kernel<<<256, 256, 0, stream>>>(partial, out);
}

// Round 18
// 81.123 us; speedup vs baseline: 1.0139x; 1.0139x over previous
//
#include <hip/hip_runtime.h>
#include <hip/hip_bf16.h>

#define TDEPTH 6
#define NLEAF 64
#define NGATE 63
#define INF 512
#define OUTF 512
#define BATCH 1024
#define SPLITK 16
#define NPL 32        // real planes per K-slice (512/SPLITK)

typedef _Float16 f16;
typedef __attribute__((ext_vector_type(2)))  f16 f16x2;
typedef __attribute__((ext_vector_type(8)))  f16 f16x8;
typedef __attribute__((ext_vector_type(4)))  float f32x4;
typedef __attribute__((ext_vector_type(16))) float f32x16;

__device__ __forceinline__ f16x8 pack8h(f32x4 a, f32x4 b) {
  f16x8 w;
  w[0] = (f16)a[0]; w[1] = (f16)a[1]; w[2] = (f16)a[2]; w[3] = (f16)a[3];
  w[4] = (f16)b[0]; w[5] = (f16)b[1]; w[6] = (f16)b[2]; w[7] = (f16)b[3];
  return w;
}

// ---------------- kernel 1: leaf + coalesced pwh pack (r17, verified) -----
__global__ __launch_bounds__(256) void prep_kernel(
    const float* __restrict__ x, const float* __restrict__ gw,
    const float* __restrict__ gb, const float* __restrict__ pw,
    const float* __restrict__ pb, float* __restrict__ leaf,
    f16* __restrict__ pwh) {
  const int tid = threadIdx.x;
  if (blockIdx.x < 256) {
    const int wid = tid >> 6, lane = tid & 63;
    const int b = blockIdx.x * 4 + wid;
    __shared__ float g[4][NLEAF];
    if (lane < NGATE) {
      const float* xr = x + (size_t)b * INF;
      float a0 = 0.f, a1 = 0.f, a2 = 0.f, a3 = 0.f;
      #pragma unroll 4
      for (int i = 0; i < INF; i += 4) {
        a0 += xr[i + 0] * gw[(i + 0) * NGATE + lane];
        a1 += xr[i + 1] * gw[(i + 1) * NGATE + lane];
        a2 += xr[i + 2] * gw[(i + 2) * NGATE + lane];
        a3 += xr[i + 3] * gw[(i + 3) * NGATE + lane];
      }
      float t = (a0 + a1) + (a2 + a3) + gb[lane];
      g[wid][lane] = 1.0f / (1.0f + __expf(-t));
    }
    __syncthreads();
    float p = 1.0f;
    #pragma unroll
    for (int d = 0; d < TDEPTH; d++) {
      int prefix = lane >> (TDEPTH - 1 - d);
      int node = (1 << d) - 1 + (prefix >> 1);
      float gv = g[wid][node];
      p *= (prefix & 1) ? (1.0f - gv) : gv;
    }
    leaf[(size_t)b * NLEAF + lane] = p;
    return;
  }
  if (blockIdx.x < 768) {  // pw: source-coalesced granule remap
    const unsigned base = (blockIdx.x - 256) * 4096;
    #pragma unroll
    for (int rep = 0; rep < 16; rep++) {
      const unsigned T = base + rep * 256 + tid;
      const unsigned o = T >> 12, rem = T & 4095;
      const unsigned i = rem >> 3, kg = rem & 7;
      const float* src = pw + (size_t)T * 8;
      f32x4 a = *(const f32x4*)src, b = *(const f32x4*)(src + 4);
      const unsigned r = o & 15;
      const unsigned p = ((((o >> 4) & 1) << 3) | kg) ^ r;
      char* dst = (char*)pwh + (((size_t)((o >> 5) * 513 + i)) << 12) +
                  r * 256 + p * 16;
      *(f16x8*)dst = pack8h(a, b);
    }
  } else {  // pb as plane 512
    #pragma unroll
    for (int rep = 0; rep < 16; rep++) {
      const unsigned T = rep * 256 + tid;
      const unsigned o = T >> 3, kg = T & 7;
      const float* src = pb + (size_t)T * 8;
      f32x4 a = *(const f32x4*)src, b = *(const f32x4*)(src + 4);
      const unsigned r = o & 15;
      const unsigned p = ((((o >> 4) & 1) << 3) | kg) ^ r;
      char* dst = (char*)pwh + (((size_t)((o >> 5) * 513 + 512)) << 12) +
                  r * 256 + p * 16;
      *(f16x8*)dst = pack8h(a, b);
    }
  }
}

// async 16B global -> LDS (wave-uniform LDS base; +lane*16 implicit)
__device__ __forceinline__ void gload_lds16(const void* g, void* l) {
  __builtin_amdgcn_global_load_lds(
      (const __attribute__((address_space(1))) void*)g,
      (__attribute__((address_space(3))) void*)l, 16, 0, 0);
}

// ---------------- kernel 2: barrier-free 1-wave GEMM, 12 KB LDS -----------
// acc[o,b] += sum_l pw[o,i,l] * (x[b,i]*leaf[b,l]) via
// mfma(A = pw frag from LDS, B = lfb * x-pair, C = acc).
// x packed in 4 KB LDS (u32 per plane per b-pair); 2x4KB tile buffers,
// depth-1 staging, counted vmcnt(4), lgkm WAR guard, NO barriers.
// 12 KB -> 13 blocks/CU = 3.25 waves/SIMD.
__global__ __launch_bounds__(64, 3) void gemm_kernel(
    const f16* __restrict__ pwh, const float* __restrict__ x,
    const float* __restrict__ leaf, float* __restrict__ partial) {
  __shared__ __align__(16) char Bsm[2][4096];
  __shared__ __align__(4) unsigned short xpk[NPL][64];  // 4 KB

  const int lane = threadIdx.x;
  const int lo = lane & 31, half = lane >> 5;

  // XCD-chunked: XCD c covers s in {2c,2c+1} (working set ~4.2MB ~ its L2)
  const int L = ((int)blockIdx.x & 7) * 512 + ((int)blockIdx.x >> 3);
  const int s = L >> 8;
  const int rem = L & 255;
  const int ot = rem >> 4, bt = rem & 15;
  const int b0 = bt * 64;
  const int cs = s * NPL;

  // stage x -> packed f16 pairs: u32 word [t][e] = f16(x[b0+e]) | f16(x[b0+32+e])<<16
  {
    const float* xr = x + (size_t)(b0 + lane) * INF + cs;
    const int pos = (lane < 32) ? (2 * lane) : (2 * (lane - 32) + 1);
    #pragma unroll
    for (int c4 = 0; c4 < NPL / 4; c4++) {
      f32x4 v = *(const f32x4*)(xr + c4 * 4);
      #pragma unroll
      for (int j = 0; j < 4; j++)
        xpk[c4 * 4 + j][pos] = __builtin_bit_cast(unsigned short, (f16)v[j]);
    }
  }

  // resident leaf B-fragments (f16): col = b, k-octet = half
  f16x8 lfb[2][4];
  #pragma unroll
  for (int mt = 0; mt < 2; mt++) {
    const float* lr = leaf + (size_t)(b0 + mt * 32 + lo) * NLEAF + half * 8;
    #pragma unroll
    for (int t4 = 0; t4 < 4; t4++)
      lfb[mt][t4] = pack8h(*(const f32x4*)(lr + t4 * 16),
                           *(const f32x4*)(lr + t4 * 16 + 4));
  }

  // per-lane LDS read offsets (loop-invariant)
  unsigned rdoff[4];
  {
    const unsigned r = (unsigned)(lo & 15);
    const unsigned hb = ((unsigned)(lo >> 4)) * 128 + (unsigned)half * 16;
    #pragma unroll
    for (int t4 = 0; t4 < 4; t4++)
      rdoff[t4] = r * 256 + ((hb + t4 * 32) ^ (r << 4));
  }

  const char* tb = (const char*)pwh + ((size_t)(ot * 513 + cs) << 12) +
                   (size_t)lane * 16;
  char* bufA = (char*)&Bsm[0][0];
  char* bufB = (char*)&Bsm[1][0];
  const unsigned* xw = (const unsigned*)&xpk[0][0];

  f32x16 acc0 = (f32x16)(0.f), acc1 = (f32x16)(0.f);

  auto stage = [&](char* dstb, int t) {
    const char* srcb = tb + ((size_t)t << 12);
    #pragma unroll
    for (int j = 0; j < 4; j++)
      gload_lds16(srcb + j * 1024, dstb + j * 1024);
  };

  auto mfma_step = [&](const char* bufc, unsigned pr0, unsigned pr1) {
    f16x2 v0 = __builtin_bit_cast(f16x2, pr0);
    f16x2 v1 = __builtin_bit_cast(f16x2, pr1);
    f16x8 xv80 = __builtin_shufflevector(v0, v0, 0, 1, 0, 1, 0, 1, 0, 1);
    f16x8 xv81 = __builtin_shufflevector(v1, v1, 0, 1, 0, 1, 0, 1, 0, 1);
    #pragma unroll
    for (int t4 = 0; t4 < 4; t4++) {
      f16x8 af = *(const f16x8*)(bufc + rdoff[t4]);
      f16x8 s0 = lfb[0][t4] * xv80;
      f16x8 s1 = lfb[1][t4] * xv81;
      acc0 = __builtin_amdgcn_mfma_f32_32x32x16_f16(af, s0, acc0, 0, 0, 0);
      acc1 = __builtin_amdgcn_mfma_f32_32x32x16_f16(af, s1, acc1, 0, 0, 0);
    }
  };

  auto xpair = [&](int t, unsigned& p0, unsigned& p1) {
    const unsigned u = xw[t * 32 + lo];   // broadcast across half
    p0 = (u & 0xffffu); p0 |= (p0 << 16);
    p1 = (u >> 16);     p1 |= (p1 << 16);
  };

  stage(bufA, 0);

  for (int t = 0; t < NPL; t += 2) {
    unsigned p0, p1;
    // --- step t (compute from bufA, stage t+1 into bufB) ---
    __builtin_amdgcn_sched_barrier(0);
    asm volatile("s_waitcnt lgkmcnt(0)" ::: "memory");  // WAR: bufB reads done
    __builtin_amdgcn_sched_barrier(0);
    stage(bufB, t + 1);
    __builtin_amdgcn_sched_barrier(0);
    asm volatile("s_waitcnt vmcnt(4)" ::: "memory");    // stage(t) landed
    __builtin_amdgcn_sched_barrier(0);
    xpair(t, p0, p1);
    mfma_step(bufA, p0, p1);
    // --- step t+1 (compute from bufB, stage t+2 into bufA) ---
    __builtin_amdgcn_sched_barrier(0);
    asm volatile("s_waitcnt lgkmcnt(0)" ::: "memory");  // WAR: bufA reads done
    __builtin_amdgcn_sched_barrier(0);
    stage(bufA, t + 2);   // plane cs+t+2 <= 512 always valid
    __builtin_amdgcn_sched_barrier(0);
    asm volatile("s_waitcnt vmcnt(4)" ::: "memory");    // stage(t+1) landed
    __builtin_amdgcn_sched_barrier(0);
    xpair(t + 1, p0, p1);
    mfma_step(bufB, p0, p1);
  }

  if (s == SPLITK - 1) {  // bias plane 512 (staged into bufA at t=NPL-1)
    __builtin_amdgcn_sched_barrier(0);
    asm volatile("s_waitcnt vmcnt(0)" ::: "memory");
    __builtin_amdgcn_sched_barrier(0);
    mfma_step(bufA, 0x3C003C00u, 0x3C003C00u);          // x == 1.0 (f16)
  }

  // epilogue: partial[s][o][b] (transposed), coalesced over b = lo
  float* dstb = partial + ((size_t)s * OUTF + ot * 32) * BATCH + b0;
  #pragma unroll
  for (int e = 0; e < 16; e++) {
    int row = (e & 3) + 8 * (e >> 2) + 4 * half;
    dstb[(size_t)row * BATCH + lo] = acc0[e];
    dstb[(size_t)row * BATCH + 32 + lo] = acc1[e];
  }
}

// ---------------- kernel 3: split-K reduce + transpose ----------------
__global__ __launch_bounds__(256) void reduce_kernel(
    const float* __restrict__ partial, float* __restrict__ out) {
  __shared__ float tile[32][65];
  const int t = threadIdx.x;
  const int O0 = ((int)blockIdx.x >> 4) * 32;
  const int B0 = ((int)blockIdx.x & 15) * 64;
  #pragma unroll
  for (int rep = 0; rep < 8; rep++) {
    const int idx = rep * 256 + t;
    const int o = idx >> 6, b = idx & 63;
    float sum = 0.f;
    #pragma unroll
    for (int s = 0; s < SPLITK; s++)
      sum += partial[((size_t)s * OUTF + O0 + o) * BATCH + B0 + b];
    tile[o][b] = sum;
  }
  __syncthreads();
  #pragma unroll
  for (int rep = 0; rep < 8; rep++) {
    const int idx = rep * 256 + t;
    const int b = idx >> 5, o = idx & 31;
    out[(size_t)(B0 + b) * OUTF + O0 + o] = tile[o][b];
  }
}

extern "C" void kernel_launch(void* const* d_in, const int* in_sizes, int n_in,
                              void* d_out, int out_size, void* d_ws, size_t ws_size,
                              hipStream_t stream) {
  const float* x  = (const float*)d_in[0];
  const float* gw = (const float*)d_in[1];
  const float* gb = (const float*)d_in[2];
  const float* pw = (const float*)d_in[3];
  const float* pb = (const float*)d_in[4];
  float* out = (float*)d_out;

  float* leaf    = (float*)d_ws;                          // 256 KB
  f16*   pwh     = (f16*)((char*)d_ws + (256 << 10));     // 33.62 MB
  float* partial = (float*)((char*)d_ws + (256 << 10) + (size_t)16 * 513 * 4096);

  prep_kernel<<<769, 256, 0, stream>>>(x, gw, gb, pw, pb, leaf, pwh);
  gemm_kernel<<<4096, 64, 0, stream>>>(pwh, x, leaf, partial);
  reduce_kernel<<<256, 256, 0, stream>>>(partial, out);
}